// Round 12
// baseline (122.187 us; speedup 1.0000x reference)
//
#include <hip/hip_runtime.h>
#include <hip/hip_bf16.h>
#include <cstdint>

typedef unsigned short u16;
typedef __attribute__((ext_vector_type(8))) short bf16x8;
typedef __attribute__((ext_vector_type(4))) float f32x4;

#define NB 64
#define NN 197
#define NC 768
#define NH 12
#define ND 64
#define NM (NB*NN)   // 12608
#define CAP 96       // per-batch cap (mean ~26, 15-sigma safe)
#define NT 24        // K-loop tiles (NC/32)
#define SELR 6144    // NB*CAP max compacted rows
#define MT256 24     // SELR/256 m-tiles worst case
#define ASZ ((size_t)NM*NC)
#define WSZ ((size_t)NC*NC)
#define SELSZ2 ((size_t)SELR*NC)

__device__ __forceinline__ u16 f2bf(float f) {
  uint32_t u = __float_as_uint(f);
  u += 0x7fffu + ((u >> 16) & 1u);
  return (u16)(u >> 16);
}

__device__ __forceinline__ void gl_lds16(const u16* g, u16* l) {
  __builtin_amdgcn_global_load_lds(
      (const __attribute__((address_space(1))) void*)g,
      (__attribute__((address_space(3))) void*)l, 16, 0, 0);
}

// ============ unified 256x128 GEMM block body, 512 threads (8 waves) ========
// OUTM: 0 = bf16 store (bound-guarded), 1 = f32 dense (ts<0.5 predicate + bias),
//       2 = f32 scatter via gidxOut + bias
template<int GATHER, int OUTM>
__device__ __forceinline__ void gemm256_body(
    const u16* __restrict__ A, const u16* __restrict__ B,
    u16* __restrict__ obf, float* __restrict__ of32,
    const float* __restrict__ bias, const float* __restrict__ ts,
    const int* __restrict__ gidx, int m0, int n0, int bound,
    u16* SAf, u16* SBf) {
  int tid = threadIdx.x, lane = tid & 63, wave = tid >> 6;
  int lr = lane & 15, lg = lane >> 4, lk = lg * 8;
  int wr = (wave >> 1) * 64, wc = (wave & 1) * 64;
  int idA0 = tid, idA1 = 512 + tid, idB = tid;
  const u16 *baseA0, *baseA1;
  if (GATHER) {
    baseA0 = A + (size_t)gidx[m0 + (idA0 >> 2)] * NC + (idA0 & 3) * 8;
    baseA1 = A + (size_t)gidx[m0 + (idA1 >> 2)] * NC + (idA1 & 3) * 8;
  } else {
    baseA0 = A + (size_t)(m0 + (idA0 >> 2)) * NC + (idA0 & 3) * 8;
    baseA1 = A + (size_t)(m0 + (idA1 >> 2)) * NC + (idA1 & 3) * 8;
  }
  const u16* baseB0 = B + (size_t)(n0 + (idB >> 2)) * NC + (idB & 3) * 8;
  u16* dA0 = SAf + (size_t)idA0 * 8;
  u16* dA1 = SAf + (size_t)idA1 * 8;
  u16* dB0 = SBf + (size_t)idB * 8;

  f32x4 acc[4][4];
  #pragma unroll
  for (int i = 0; i < 4; ++i)
    #pragma unroll
    for (int j = 0; j < 4; ++j) acc[i][j] = (f32x4){0.f,0.f,0.f,0.f};

  for (int k0 = 0; k0 < NC; k0 += 32) {
    gl_lds16(baseA0 + k0, dA0);
    gl_lds16(baseA1 + k0, dA1);
    gl_lds16(baseB0 + k0, dB0);
    __syncthreads();
    bf16x8 af[4], bfr[4];
    #pragma unroll
    for (int f = 0; f < 4; ++f) {
      af[f]  = *(const bf16x8*)(SAf + (size_t)(wr + f*16 + lr) * 32 + lk);
      bfr[f] = *(const bf16x8*)(SBf + (size_t)(wc + f*16 + lr) * 32 + lk);
    }
    #pragma unroll
    for (int i = 0; i < 4; ++i)
      #pragma unroll
      for (int j = 0; j < 4; ++j)
        acc[i][j] = __builtin_amdgcn_mfma_f32_16x16x32_bf16(af[i], bfr[j], acc[i][j], 0, 0, 0);
    __syncthreads();
  }

  #pragma unroll
  for (int i = 0; i < 4; ++i) {
    int rbase = m0 + wr + i*16 + 4*lg;
    #pragma unroll
    for (int j = 0; j < 4; ++j) {
      int col = n0 + wc + j*16 + lr;
      #pragma unroll
      for (int r = 0; r < 4; ++r) {
        int row = rbase + r;
        if (OUTM == 0) {
          if (row < bound) obf[(size_t)row * NC + col] = f2bf(acc[i][j][r]);
        } else if (OUTM == 1) {
          if (row < NM && ts[row] < 0.5f)
            of32[(size_t)row * NC + col] = acc[i][j][r] + bias[col];
        } else {
          if (row < bound) {
            int grow = gidx[row];
            of32[(size_t)grow * NC + col] = acc[i][j][r] + bias[col];
          }
        }
      }
    }
  }
}

// ===================== K1: fused gate+cvt-x | cvt weights | trans Wv ========
#define GATEB 3152   // NM/4 (one row per wave)
#define WBLK 576     // WSZ/4/256 (exact)
#define TRBLK 144
__global__ __launch_bounds__(256) void k1_prep(const float* __restrict__ x,
    const float* __restrict__ g1, const float* __restrict__ g2,
    const float* __restrict__ Wm, const float* __restrict__ bm,
    const float* __restrict__ wq, const float* __restrict__ wk,
    const float* __restrict__ wv, const float* __restrict__ wp,
    u16* __restrict__ xb, u16* __restrict__ wqb, u16* __restrict__ wkb,
    u16* __restrict__ wvb, u16* __restrict__ wpb, u16* __restrict__ wvt,
    float* __restrict__ ts) {
  __shared__ u16 T[64][72];
  int bid = blockIdx.x, tid = threadIdx.x;

  if (bid < GATEB) {          // ---- fused: cvt x row -> bf16 AND gate dot
    int wave = tid >> 6, lane = tid & 63;
    int wid = bid * 4 + wave;
    int b = wid / NN, n = wid % NN;
    const float* xr = x + (size_t)wid * NC;
    u16* xbr = xb + (size_t)wid * NC;
    double acc = 0.0;
    #pragma unroll
    for (int i = 0; i < 3; ++i) {
      float4 f = *(const float4*)(xr + lane * 4 + 256 * i);
      float4 w = *(const float4*)(Wm + lane * 4 + 256 * i);
      acc += (double)f.x * w.x + (double)f.y * w.y
           + (double)f.z * w.z + (double)f.w * w.w;
      ushort4 o;
      o.x = f2bf(f.x); o.y = f2bf(f.y); o.z = f2bf(f.z); o.w = f2bf(f.w);
      *(ushort4*)(xbr + lane * 4 + 256 * i) = o;
    }
    #pragma unroll
    for (int off = 32; off; off >>= 1) acc += __shfl_down(acc, off);
    float o = 1.0f;
    if (n != 0) {
      double z = (acc + (double)bm[0] + (double)g1[b*(NN-1) + n - 1]
                                      - (double)g2[b*(NN-1) + n - 1]) / 5.0;
      o = (z > 0.4054651081081643820) ? 1.0f : 0.0f;  // sigmoid(z)>0.6
    }
    if (lane == 0) ts[wid] = o;
    return;
  }
  bid -= GATEB;
  if (bid < 4*WBLK) {                      // ---- cvt weights
    int seg = bid / WBLK;
    int i = (bid - seg * WBLK) * 256 + tid;
    const float* src; u16* dst;
    if (seg == 0)      { src = wq; dst = wqb; }
    else if (seg == 1) { src = wk; dst = wkb; }
    else if (seg == 2) { src = wv; dst = wvb; }
    else               { src = wp; dst = wpb; }
    float4 f = ((const float4*)src)[i];
    ushort4 o;
    o.x = f2bf(f.x); o.y = f2bf(f.y); o.z = f2bf(f.z); o.w = f2bf(f.w);
    ((ushort4*)dst)[i] = o;
    return;
  }
  bid -= 4*WBLK;                           // ---- transpose Wv -> wvt (bf16)
  {
    int bx = bid % 12, by = bid / 12;
    int j0 = by * 64, k0 = bx * 64;
    #pragma unroll
    for (int g = 0; g < 4; ++g) {
      int r = g * 16 + (tid >> 4);
      int c4 = (tid & 15) * 4;
      float4 f = *(const float4*)(wv + (size_t)(j0 + r) * NC + k0 + c4);
      T[c4 + 0][r] = f2bf(f.x);
      T[c4 + 1][r] = f2bf(f.y);
      T[c4 + 2][r] = f2bf(f.z);
      T[c4 + 3][r] = f2bf(f.w);
    }
    __syncthreads();
    #pragma unroll
    for (int g = 0; g < 4; ++g) {
      int r = g * 16 + (tid >> 4);
      int c4 = (tid & 15) * 4;
      ushort4 o = *(ushort4*)&T[r][c4];
      *(ushort4*)(wvt + (size_t)(k0 + r) * NC + j0 + c4) = o;
    }
  }
}

// ===================== CK: parallel global compaction (1 block, 1024 thr) ===
__global__ __launch_bounds__(1024) void ck_compact(const float* __restrict__ ts,
    int* __restrict__ cnt, int* __restrict__ boff, int* __restrict__ gidx) {
  __shared__ unsigned long long masks[NB][4];
  __shared__ int scnt[NB];
  __shared__ int soff[NB + 1];
  int tid = threadIdx.x, lane = tid & 63, wave = tid >> 6;  // wave 0..15

  #pragma unroll
  for (int p = 0; p < 4; ++p) {
    int b = wave * 4 + p;
    int count = 0;
    #pragma unroll
    for (int c = 0; c < 4; ++c) {
      int t = c * 64 + lane;
      bool sel = (t < NN) && (ts[b * NN + t] > 0.5f);
      unsigned long long m = __ballot(sel);
      if (lane == 0) masks[b][c] = m;
      count += __popcll(m);
    }
    if (lane == 0) scnt[b] = count < CAP ? count : CAP;
  }
  __syncthreads();

  if (wave == 0) {
    int acc = 0;
    for (int i = 0; i < NB; ++i) {
      int v = scnt[i];
      if (i < lane) acc += v;
    }
    soff[lane] = acc;
    if (lane == 63) soff[NB] = acc + scnt[63];
  }
  __syncthreads();

  #pragma unroll
  for (int p = 0; p < 4; ++p) {
    int b = wave * 4 + p;
    int base = soff[b];
    int cc = scnt[b];
    int prior = 0;
    #pragma unroll
    for (int c = 0; c < 4; ++c) {
      unsigned long long m = masks[b][c];
      int t = c * 64 + lane;
      bool sel = ((m >> lane) & 1ull) != 0;
      int within = __popcll(m & ((lane == 0) ? 0ull : (~0ull >> (64 - lane))));
      int pos = prior + within;
      if (sel && pos < cc) gidx[base + pos] = b * NN + t;
      prior += __popcll(m);
    }
  }
  if (tid < NB) { cnt[tid] = scnt[tid]; boff[tid] = soff[tid]; }
  if (tid == NB) boff[NB] = soff[NB];
  __syncthreads();
  int total = soff[NB];
  for (int i = total + tid; i < SELR; i += 1024) gidx[i] = 0;
}

// ===================== K2: gemm_sel-global (432) | Wvp GEMM (18) ============
__global__ __launch_bounds__(512) void k2_wvp_qkv(const u16* __restrict__ xb,
    const u16* __restrict__ wq3, const u16* __restrict__ wpb,
    const u16* __restrict__ wvt, u16* __restrict__ wvpb,
    u16* __restrict__ sel3, const int* __restrict__ boff,
    const int* __restrict__ gidx) {
  alignas(16) __shared__ u16 SA[256][32];
  alignas(16) __shared__ u16 SB[128][32];
  int bid = blockIdx.x;
  if (bid < MT256 * 18) {
    int mt = bid / 18, r18 = bid % 18;
    int z = r18 / 6, y = r18 % 6;
    int total = boff[NB];
    int m0 = mt * 256;
    if (m0 >= total) return;
    gemm256_body<1, 0>(xb, wq3 + (size_t)z * WSZ,
                       sel3 + (size_t)z * SELSZ2, nullptr, nullptr, nullptr,
                       gidx, m0, y * 128, total, &SA[0][0], &SB[0][0]);
  } else {
    int wb = bid - MT256 * 18;               // 0..17
    gemm256_body<0, 0>(wpb, wvt, wvpb, nullptr, nullptr, nullptr,
                       nullptr, (wb / 6) * 256, (wb % 6) * 128, NC,
                       &SA[0][0], &SB[0][0]);
  }
}

// ===================== K3: dense part-1 (192) | attn (768) ==================
#define DTOT 300   // 50 m-tiles x 6 n-tiles, XCD-chunked (q=37, r=4)
#define DN1 192
#define DN2 (DTOT-DN1)  // 108
__global__ __launch_bounds__(512) void k3_dense_attn(const u16* __restrict__ xb,
    const u16* __restrict__ wvpb, const u16* __restrict__ qsel,
    const u16* __restrict__ ksel, const u16* __restrict__ vsel,
    u16* __restrict__ zsel, const float* __restrict__ ts,
    const float* __restrict__ bp, float* __restrict__ out,
    const int* __restrict__ cnt, const int* __restrict__ boff) {
  alignas(16) __shared__ u16 LDSU[12288];   // 24KB: dense SA+SB; attn Vt
  int bid = blockIdx.x;
  int tid = threadIdx.x, lane = tid & 63, wave = tid >> 6;
  int lr = lane & 15, lg = lane >> 4;

  if (bid < DN1) {
    int xcd = bid & 7, loc = bid >> 3;
    int wgid = (xcd < 4 ? xcd * 38 : 152 + (xcd - 4) * 37) + loc;
    gemm256_body<0, 1>(xb, wvpb, nullptr, out, bp, ts, nullptr,
                       (wgid / 6) * 256, (wgid % 6) * 128, NM,
                       &LDSU[0], &LDSU[8192]);
    return;
  }

  // ---- attention per (b,h) over compact rows (8 waves; 0..5 active in loop)
  u16 (*Vt)[136] = reinterpret_cast<u16(*)[136]>(&LDSU[0]);  // 64x136 = 17.4KB
  int bh = bid - DN1;
  int b = bh / NH, h = bh % NH;
  int cntb = cnt[b];
  int boffb = boff[b];
  const size_t qbase = (size_t)boffb * NC + (size_t)h * ND;

  for (int id = tid; id < cntb * 8; id += 512) {
    int i = id >> 3, c8 = (id & 7) * 8;
    int4 val = *(const int4*)(vsel + qbase + (size_t)i * NC + c8);
    u16 tmp[8];
    *(int4*)tmp = val;
    #pragma unroll
    for (int e = 0; e < 8; ++e) Vt[c8 + e][i] = tmp[e];
  }
  for (int id = tid; id < 64 * 32; id += 512)
    Vt[id >> 5][cntb + (id & 31)] = 0;
  __syncthreads();

  int nchunk = (cntb + 15) >> 4;
  int mtmax  = nchunk;
  int mcmax  = (cntb + 31) >> 5;
  int idx0 = (((lane & 15) | ((lane & 16) << 1))) << 2;
  int idx1 = idx0 + 64;

  for (int qc = wave; qc < nchunk; qc += 8) {
    const u16* qp = qsel + qbase + (size_t)(qc * 16 + lr) * NC + lg * 8;
    bf16x8 qf0 = *(const bf16x8*)(qp);
    bf16x8 qf1 = *(const bf16x8*)(qp + 32);

    f32x4 s[6];
    #pragma unroll
    for (int mt = 0; mt < 6; ++mt) s[mt] = (f32x4){0.f,0.f,0.f,0.f};
    #pragma unroll
    for (int mt = 0; mt < 6; ++mt) {
      if (mt < mtmax) {
        const u16* kp = ksel + qbase + (size_t)(mt * 16 + lr) * NC + lg * 8;
        bf16x8 kf0 = *(const bf16x8*)(kp);
        bf16x8 kf1 = *(const bf16x8*)(kp + 32);
        f32x4 a = (f32x4){0.f,0.f,0.f,0.f};
        a = __builtin_amdgcn_mfma_f32_16x16x32_bf16(kf0, qf0, a, 0, 0, 0);
        a = __builtin_amdgcn_mfma_f32_16x16x32_bf16(kf1, qf1, a, 0, 0, 0);
        s[mt] = a;
      }
    }

    float mx = -3e38f;
    #pragma unroll
    for (int mt = 0; mt < 6; ++mt)
      #pragma unroll
      for (int jj = 0; jj < 4; ++jj) {
        int mm = mt*16 + 4*lg + jj;
        float val = (mm < cntb) ? s[mt][jj] * 0.125f : -1e30f;
        s[mt][jj] = val;
        mx = fmaxf(mx, val);
      }
    mx = fmaxf(mx, __shfl_xor(mx, 16));
    mx = fmaxf(mx, __shfl_xor(mx, 32));
    float sum = 0.f;
    #pragma unroll
    for (int mt = 0; mt < 6; ++mt)
      #pragma unroll
      for (int jj = 0; jj < 4; ++jj) {
        float pv = __expf(s[mt][jj] - mx);
        s[mt][jj] = pv;
        sum += pv;
      }
    sum += __shfl_xor(sum, 16);
    sum += __shfl_xor(sum, 32);
    float inv = 1.0f / sum;

    uint32_t u[6][2];
    #pragma unroll
    for (int mt = 0; mt < 6; ++mt) {
      u[mt][0] = ((uint32_t)f2bf(s[mt][1]*inv) << 16) | f2bf(s[mt][0]*inv);
      u[mt][1] = ((uint32_t)f2bf(s[mt][3]*inv) << 16) | f2bf(s[mt][2]*inv);
    }

    f32x4 oacc[4];
    #pragma unroll
    for (int dt = 0; dt < 4; ++dt) oacc[dt] = (f32x4){0.f,0.f,0.f,0.f};
    #pragma unroll
    for (int mc = 0; mc < 3; ++mc) {
      if (mc < mcmax) {
        uint32_t a0 = (uint32_t)__builtin_amdgcn_ds_bpermute(idx0, (int)u[2*mc][0]);
        uint32_t b0 = (uint32_t)__builtin_amdgcn_ds_bpermute(idx0, (int)u[2*mc+1][0]);
        uint32_t a1 = (uint32_t)__builtin_amdgcn_ds_bpermute(idx0, (int)u[2*mc][1]);
        uint32_t b1 = (uint32_t)__builtin_amdgcn_ds_bpermute(idx0, (int)u[2*mc+1][1]);
        uint32_t a2 = (uint32_t)__builtin_amdgcn_ds_bpermute(idx1, (int)u[2*mc][0]);
        uint32_t b2 = (uint32_t)__builtin_amdgcn_ds_bpermute(idx1, (int)u[2*mc+1][0]);
        uint32_t a3 = (uint32_t)__builtin_amdgcn_ds_bpermute(idx1, (int)u[2*mc][1]);
        uint32_t b3 = (uint32_t)__builtin_amdgcn_ds_bpermute(idx1, (int)u[2*mc+1][1]);
        bool hi = (lg >= 2);
        union { uint32_t w[4]; bf16x8 v; } pu;
        pu.w[0] = hi ? b0 : a0;
        pu.w[1] = hi ? b1 : a1;
        pu.w[2] = hi ? b2 : a2;
        pu.w[3] = hi ? b3 : a3;
        bf16x8 pa = pu.v;
        #pragma unroll
        for (int dt = 0; dt < 4; ++dt) {
          bf16x8 vf = *(const bf16x8*)(&Vt[dt*16 + lr][mc*32 + lg*8]);
          oacc[dt] = __builtin_amdgcn_mfma_f32_16x16x32_bf16(pa, vf, oacc[dt], 0, 0, 0);
        }
      }
    }

    #pragma unroll
    for (int r = 0; r < 4; ++r) {
      int nloc = qc*16 + 4*lg + r;
      if (nloc < cntb) {
        u16* op = zsel + qbase + (size_t)nloc * NC + lr;
        #pragma unroll
        for (int dt = 0; dt < 4; ++dt)
          op[dt*16] = f2bf(oacc[dt][r]);
      }
    }
  }
}

// ===================== K4: proj-global (144) | dense part-2 (108) ===========
#define PJBLK (MT256*6)  // 144
__global__ __launch_bounds__(512) void k4_out(const u16* __restrict__ xb,
    const u16* __restrict__ wvpb, const u16* __restrict__ zsel,
    const u16* __restrict__ wpb, const float* __restrict__ ts,
    const float* __restrict__ bp, float* __restrict__ out,
    const int* __restrict__ boff, const int* __restrict__ gidx) {
  alignas(16) __shared__ u16 SA[256][32];
  alignas(16) __shared__ u16 SB[128][32];
  int bid = blockIdx.x;
  if (bid < PJBLK) {
    int mt = bid / 6, y = bid % 6;
    int total = boff[NB];
    int m0 = mt * 256;
    if (m0 >= total) return;
    gemm256_body<0, 2>(zsel, wpb, nullptr, out, bp, nullptr,
                       gidx, m0, y * 128, total, &SA[0][0], &SB[0][0]);
  } else {
    int d = DN1 + (bid - PJBLK);            // 192..299
    int xcd = d & 7, loc = d >> 3;
    int wgid = (xcd < 4 ? xcd * 38 : 152 + (xcd - 4) * 37) + loc;
    gemm256_body<0, 1>(xb, wvpb, nullptr, out, bp, ts, nullptr,
                       (wgid / 6) * 256, (wgid % 6) * 128, NM,
                       &SA[0][0], &SB[0][0]);
  }
}

// ---------------------------------------------------------------------------
extern "C" void kernel_launch(void* const* d_in, const int* in_sizes, int n_in,
                              void* d_out, int out_size, void* d_ws, size_t ws_size,
                              hipStream_t stream) {
  const float* x  = (const float*)d_in[0];
  const float* g1 = (const float*)d_in[1];
  const float* g2 = (const float*)d_in[2];
  const float* Wq = (const float*)d_in[3];
  const float* Wk = (const float*)d_in[4];
  const float* Wv = (const float*)d_in[5];
  const float* Wp = (const float*)d_in[6];
  const float* bp = (const float*)d_in[7];
  const float* Wm = (const float*)d_in[8];
  const float* bm = (const float*)d_in[9];
  float* out = (float*)d_out;

  const size_t act_sz = ASZ * 2;
  const size_t w_sz   = WSZ * 2;
  const size_t sel_sz = SELSZ2 * 2;
  size_t need = act_sz + 4*sel_sz + 6*w_sz + (size_t)NM*4
              + (size_t)(NB+1)*4 + (size_t)NB*4 + (size_t)SELR*4 + 256;
  if (ws_size < need) return;

  char* p = (char*)d_ws;
  u16* xb   = (u16*)p; p += act_sz;
  u16* qsel = (u16*)p; p += sel_sz;    // qsel,ksel,vsel consecutive (z*SELSZ2)
  u16* ksel = (u16*)p; p += sel_sz;
  u16* vsel = (u16*)p; p += sel_sz;
  u16* zsel = (u16*)p; p += sel_sz;
  u16* wqb  = (u16*)p; p += w_sz;      // wqb,wkb,wvb consecutive (z*WSZ)
  u16* wkb  = (u16*)p; p += w_sz;
  u16* wvb  = (u16*)p; p += w_sz;
  u16* wpb  = (u16*)p; p += w_sz;
  u16* wvtb = (u16*)p; p += w_sz;      // Wv^T bf16
  u16* wvpb = (u16*)p; p += w_sz;      // Wvp = Wp @ Wv
  float* ts = (float*)p; p += (size_t)NM*4;
  int* cnt  = (int*)p;  p += (size_t)NB*4;
  int* boff = (int*)p;  p += (size_t)(NB+1)*4;
  int* gidx = (int*)p;
  (void)wkb; (void)wvb;

  // K1: fused gate+cvt-x | cvt weights | trans Wv
  k1_prep<<<dim3(GATEB + 4*WBLK + TRBLK), 256, 0, stream>>>(
      x, g1, g2, Wm, bm, Wq, Wk, Wv, Wp,
      xb, wqb, wkb, wvb, wpb, wvtb, ts);

  // CK: parallel global compaction (single 1024-thread block)
  ck_compact<<<dim3(1), 1024, 0, stream>>>(ts, cnt, boff, gidx);

  // K2: gemm_sel-global Q/K/V | Wvp GEMM (256x128 tiles, 512 thr)
  k2_wvp_qkv<<<dim3(MT256*18 + 18), 512, 0, stream>>>(
      xb, wqb, wpb, wvtb, wvpb, qsel, boff, gidx);

  // K3: dense part-1 | sparse attention -> compact zsel
  k3_dense_attn<<<dim3(DN1 + NB*NH), 512, 0, stream>>>(
      xb, wvpb, qsel, ksel, vsel, zsel, ts, bp, out, cnt, boff);

  // K4: proj-global scatter (selected) | dense part-2
  k4_out<<<dim3(PJBLK + DN2), 512, 0, stream>>>(
      xb, wvpb, zsel, wpb, ts, bp, out, boff, gidx);
}

// Round 13
// 94.890 us; speedup vs baseline: 1.2877x; 1.2877x over previous
//
#include <hip/hip_runtime.h>
#include <hip/hip_bf16.h>
#include <cstdint>

typedef unsigned short u16;
typedef __attribute__((ext_vector_type(8))) short bf16x8;
typedef __attribute__((ext_vector_type(4))) float f32x4;

#define NB 64
#define NN 197
#define NC 768
#define NH 12
#define ND 64
#define NM (NB*NN)   // 12608
#define CAP 96       // per-batch cap (mean ~26, 15-sigma safe)
#define NT 24        // K-loop tiles (NC/32)
#define SELR 6144    // NB*CAP max compacted rows
#define MSELT 48     // SELR/128 m-tiles worst case
#define ASZ ((size_t)NM*NC)
#define WSZ ((size_t)NC*NC)
#define SELSZ2 ((size_t)SELR*NC)

#define WAITVM(N) asm volatile("s_waitcnt vmcnt(" #N ")" ::: "memory")
#define SBAR() __builtin_amdgcn_s_barrier()
#define SCHEDB() __builtin_amdgcn_sched_barrier(0)

__device__ __forceinline__ u16 f2bf(float f) {
  uint32_t u = __float_as_uint(f);
  u += 0x7fffu + ((u >> 16) & 1u);
  return (u16)(u >> 16);
}

__device__ __forceinline__ void gl_lds16(const u16* g, u16* l) {
  __builtin_amdgcn_global_load_lds(
      (const __attribute__((address_space(1))) void*)g,
      (__attribute__((address_space(3))) void*)l, 16, 0, 0);
}

// ======== 128x128 GEMM body, 256 thr, 3-buffer counted-vmcnt (r8-proven) ====
// OUTM: 0 = bf16 store (row<bound), 1 = f32 dense (ts<0.5 + bias),
//       2 = f32 scatter via gidx (row<bound) + bias
template<int GATHER, int OUTM>
__device__ __forceinline__ void gemm128c(
    const u16* __restrict__ A, const u16* __restrict__ B,
    u16* __restrict__ obf, float* __restrict__ of32,
    const float* __restrict__ bias, const float* __restrict__ ts,
    const int* __restrict__ gidx, int m0, int n0, int bound,
    u16 (*SA)[128][32], u16 (*SB)[128][32]) {
  int tid = threadIdx.x, lane = tid & 63, wave = tid >> 6;
  int lr = lane & 15, lg = lane >> 4, lk = lg * 8;
  int wr = (wave >> 1) * 64, wc = (wave & 1) * 64;
  int id0 = (wave*2 + 0) * 64 + lane, id1 = (wave*2 + 1) * 64 + lane;
  const u16 *baseA0, *baseA1;
  if (GATHER) {
    baseA0 = A + (size_t)gidx[m0 + (id0 >> 2)] * NC + (id0 & 3) * 8;
    baseA1 = A + (size_t)gidx[m0 + (id1 >> 2)] * NC + (id1 & 3) * 8;
  } else {
    baseA0 = A + (size_t)(m0 + (id0 >> 2)) * NC + (id0 & 3) * 8;
    baseA1 = A + (size_t)(m0 + (id1 >> 2)) * NC + (id1 & 3) * 8;
  }
  const u16* baseB0 = B + (size_t)(n0 + (id0 >> 2)) * NC + (id0 & 3) * 8;
  const u16* baseB1 = B + (size_t)(n0 + (id1 >> 2)) * NC + (id1 & 3) * 8;

  f32x4 acc[4][4];
  #pragma unroll
  for (int i = 0; i < 4; ++i)
    #pragma unroll
    for (int j = 0; j < 4; ++j) acc[i][j] = (f32x4){0.f,0.f,0.f,0.f};

  auto stage = [&](int buf, int kt) {
    int k0 = kt * 32;
    gl_lds16(baseA0 + k0, &SA[buf][0][0] + (size_t)(wave*2 + 0) * 512);
    gl_lds16(baseA1 + k0, &SA[buf][0][0] + (size_t)(wave*2 + 1) * 512);
    gl_lds16(baseB0 + k0, &SB[buf][0][0] + (size_t)(wave*2 + 0) * 512);
    gl_lds16(baseB1 + k0, &SB[buf][0][0] + (size_t)(wave*2 + 1) * 512);
  };
  auto comp = [&](int buf) {
    bf16x8 af[4], bfr[4];
    #pragma unroll
    for (int f = 0; f < 4; ++f) {
      af[f]  = *(const bf16x8*)(&SA[buf][wr + f*16 + lr][lk]);
      bfr[f] = *(const bf16x8*)(&SB[buf][wc + f*16 + lr][lk]);
    }
    #pragma unroll
    for (int i = 0; i < 4; ++i)
      #pragma unroll
      for (int j = 0; j < 4; ++j)
        acc[i][j] = __builtin_amdgcn_mfma_f32_16x16x32_bf16(af[i], bfr[j], acc[i][j], 0, 0, 0);
  };

  stage(0, 0); stage(1, 1);
  int cb = 0;
  for (int t = 0; t < NT; ++t) {
    if (t + 2 < NT) {
      int sb = cb + 2; if (sb > 2) sb -= 3;
      stage(sb, t + 2);
      WAITVM(8);
    } else if (t + 1 < NT) { WAITVM(4); }
    else { WAITVM(0); }
    SBAR(); SCHEDB();
    comp(cb);
    SBAR();
    cb = (cb == 2) ? 0 : cb + 1;
  }

  #pragma unroll
  for (int i = 0; i < 4; ++i) {
    int rbase = m0 + wr + i*16 + 4*lg;
    #pragma unroll
    for (int j = 0; j < 4; ++j) {
      int col = n0 + wc + j*16 + lr;
      #pragma unroll
      for (int r = 0; r < 4; ++r) {
        int row = rbase + r;
        if (OUTM == 0) {
          if (row < bound) obf[(size_t)row * NC + col] = f2bf(acc[i][j][r]);
        } else if (OUTM == 1) {
          if (row < NM && ts[row] < 0.5f)
            of32[(size_t)row * NC + col] = acc[i][j][r] + bias[col];
        } else {
          if (row < bound) {
            int grow = gidx[row];
            of32[(size_t)grow * NC + col] = acc[i][j][r] + bias[col];
          }
        }
      }
    }
  }
}

// ===================== K1: fused gate+cvt-x | cvt weights | trans Wv ========
#define GATEB 3152   // NM/4 (one row per wave)
#define WBLK 576     // WSZ/4/256 (exact)
#define TRBLK 144
__global__ __launch_bounds__(256) void k1_prep(const float* __restrict__ x,
    const float* __restrict__ g1, const float* __restrict__ g2,
    const float* __restrict__ Wm, const float* __restrict__ bm,
    const float* __restrict__ wq, const float* __restrict__ wk,
    const float* __restrict__ wv, const float* __restrict__ wp,
    u16* __restrict__ xb, u16* __restrict__ wqb, u16* __restrict__ wkb,
    u16* __restrict__ wvb, u16* __restrict__ wpb, u16* __restrict__ wvt,
    float* __restrict__ ts) {
  __shared__ u16 T[64][72];
  int bid = blockIdx.x, tid = threadIdx.x;

  if (bid < GATEB) {          // ---- fused: cvt x row -> bf16 AND gate dot
    int wave = tid >> 6, lane = tid & 63;
    int wid = bid * 4 + wave;
    int b = wid / NN, n = wid % NN;
    const float* xr = x + (size_t)wid * NC;
    u16* xbr = xb + (size_t)wid * NC;
    double acc = 0.0;
    #pragma unroll
    for (int i = 0; i < 3; ++i) {
      float4 f = *(const float4*)(xr + lane * 4 + 256 * i);
      float4 w = *(const float4*)(Wm + lane * 4 + 256 * i);
      acc += (double)f.x * w.x + (double)f.y * w.y
           + (double)f.z * w.z + (double)f.w * w.w;
      ushort4 o;
      o.x = f2bf(f.x); o.y = f2bf(f.y); o.z = f2bf(f.z); o.w = f2bf(f.w);
      *(ushort4*)(xbr + lane * 4 + 256 * i) = o;
    }
    #pragma unroll
    for (int off = 32; off; off >>= 1) acc += __shfl_down(acc, off);
    float o = 1.0f;
    if (n != 0) {
      double z = (acc + (double)bm[0] + (double)g1[b*(NN-1) + n - 1]
                                      - (double)g2[b*(NN-1) + n - 1]) / 5.0;
      o = (z > 0.4054651081081643820) ? 1.0f : 0.0f;  // sigmoid(z)>0.6
    }
    if (lane == 0) ts[wid] = o;
    return;
  }
  bid -= GATEB;
  if (bid < 4*WBLK) {                      // ---- cvt weights
    int seg = bid / WBLK;
    int i = (bid - seg * WBLK) * 256 + tid;
    const float* src; u16* dst;
    if (seg == 0)      { src = wq; dst = wqb; }
    else if (seg == 1) { src = wk; dst = wkb; }
    else if (seg == 2) { src = wv; dst = wvb; }
    else               { src = wp; dst = wpb; }
    float4 f = ((const float4*)src)[i];
    ushort4 o;
    o.x = f2bf(f.x); o.y = f2bf(f.y); o.z = f2bf(f.z); o.w = f2bf(f.w);
    ((ushort4*)dst)[i] = o;
    return;
  }
  bid -= 4*WBLK;                           // ---- transpose Wv -> wvt (bf16)
  {
    int bx = bid % 12, by = bid / 12;
    int j0 = by * 64, k0 = bx * 64;
    #pragma unroll
    for (int g = 0; g < 4; ++g) {
      int r = g * 16 + (tid >> 4);
      int c4 = (tid & 15) * 4;
      float4 f = *(const float4*)(wv + (size_t)(j0 + r) * NC + k0 + c4);
      T[c4 + 0][r] = f2bf(f.x);
      T[c4 + 1][r] = f2bf(f.y);
      T[c4 + 2][r] = f2bf(f.z);
      T[c4 + 3][r] = f2bf(f.w);
    }
    __syncthreads();
    #pragma unroll
    for (int g = 0; g < 4; ++g) {
      int r = g * 16 + (tid >> 4);
      int c4 = (tid & 15) * 4;
      ushort4 o = *(ushort4*)&T[r][c4];
      *(ushort4*)(wvt + (size_t)(k0 + r) * NC + j0 + c4) = o;
    }
  }
}

// ===================== CK: parallel global compaction (1 block, 1024 thr) ===
__global__ __launch_bounds__(1024) void ck_compact(const float* __restrict__ ts,
    int* __restrict__ cnt, int* __restrict__ boff, int* __restrict__ gidx) {
  __shared__ unsigned long long masks[NB][4];
  __shared__ int scnt[NB];
  __shared__ int soff[NB + 1];
  int tid = threadIdx.x, lane = tid & 63, wave = tid >> 6;  // wave 0..15

  #pragma unroll
  for (int p = 0; p < 4; ++p) {
    int b = wave * 4 + p;
    int count = 0;
    #pragma unroll
    for (int c = 0; c < 4; ++c) {
      int t = c * 64 + lane;
      bool sel = (t < NN) && (ts[b * NN + t] > 0.5f);
      unsigned long long m = __ballot(sel);
      if (lane == 0) masks[b][c] = m;
      count += __popcll(m);
    }
    if (lane == 0) scnt[b] = count < CAP ? count : CAP;
  }
  __syncthreads();

  if (wave == 0) {
    int acc = 0;
    for (int i = 0; i < NB; ++i) {
      int v = scnt[i];
      if (i < lane) acc += v;
    }
    soff[lane] = acc;
    if (lane == 63) soff[NB] = acc + scnt[63];
  }
  __syncthreads();

  #pragma unroll
  for (int p = 0; p < 4; ++p) {
    int b = wave * 4 + p;
    int base = soff[b];
    int cc = scnt[b];
    int prior = 0;
    #pragma unroll
    for (int c = 0; c < 4; ++c) {
      unsigned long long m = masks[b][c];
      int t = c * 64 + lane;
      bool sel = ((m >> lane) & 1ull) != 0;
      int within = __popcll(m & ((lane == 0) ? 0ull : (~0ull >> (64 - lane))));
      int pos = prior + within;
      if (sel && pos < cc) gidx[base + pos] = b * NN + t;
      prior += __popcll(m);
    }
  }
  if (tid < NB) { cnt[tid] = scnt[tid]; boff[tid] = soff[tid]; }
  if (tid == NB) boff[NB] = soff[NB];
  __syncthreads();
  int total = soff[NB];
  for (int i = total + tid; i < SELR; i += 1024) gidx[i] = 0;
}

// ===================== K2: gemm_sel-global (864) | Wvp GEMM (36) ============
__global__ __launch_bounds__(256) void k2_wvp_qkv(const u16* __restrict__ xb,
    const u16* __restrict__ wq3, const u16* __restrict__ wpb,
    const u16* __restrict__ wvt, u16* __restrict__ wvpb,
    u16* __restrict__ sel3, const int* __restrict__ boff,
    const int* __restrict__ gidx) {
  alignas(16) __shared__ u16 SA[3][128][32];
  alignas(16) __shared__ u16 SB[3][128][32];
  int bid = blockIdx.x;
  if (bid < MSELT * 18) {
    int mt = bid / 18, r18 = bid % 18;
    int z = r18 / 6, y = r18 % 6;
    int total = boff[NB];
    int m0 = mt * 128;
    if (m0 >= total) return;
    gemm128c<1, 0>(xb, wq3 + (size_t)z * WSZ,
                   sel3 + (size_t)z * SELSZ2, nullptr, nullptr, nullptr,
                   gidx, m0, y * 128, total, SA, SB);
  } else {
    int wb = bid - MSELT * 18;               // 0..35
    gemm128c<0, 0>(wpb, wvt, wvpb, nullptr, nullptr, nullptr,
                   nullptr, (wb / 6) * 128, (wb % 6) * 128, NC, SA, SB);
  }
}

// ===================== K3: sparse attention per (b,h), compact rows =========
__global__ __launch_bounds__(256) void attn_sel(const u16* __restrict__ qsel,
    const u16* __restrict__ ksel, const u16* __restrict__ vsel,
    u16* __restrict__ zsel, const int* __restrict__ cnt,
    const int* __restrict__ boff) {
  alignas(16) __shared__ u16 Vt[64][136];   // 17.4KB; stride 68dw -> 2-way max
  int bh = blockIdx.x;
  int b = bh / NH, h = bh % NH;
  int cntb = cnt[b];
  int boffb = boff[b];
  int tid = threadIdx.x, lane = tid & 63, wave = tid >> 6;
  int lr = lane & 15, lg = lane >> 4;
  const size_t qbase = (size_t)boffb * NC + (size_t)h * ND;

  for (int id = tid; id < cntb * 8; id += 256) {
    int i = id >> 3, c8 = (id & 7) * 8;
    int4 val = *(const int4*)(vsel + qbase + (size_t)i * NC + c8);
    u16 tmp[8];
    *(int4*)tmp = val;
    #pragma unroll
    for (int e = 0; e < 8; ++e) Vt[c8 + e][i] = tmp[e];
  }
  for (int id = tid; id < 64 * 32; id += 256)
    Vt[id >> 5][cntb + (id & 31)] = 0;
  __syncthreads();

  int nchunk = (cntb + 15) >> 4;
  int mtmax  = nchunk;
  int mcmax  = (cntb + 31) >> 5;
  int idx0 = (((lane & 15) | ((lane & 16) << 1))) << 2;
  int idx1 = idx0 + 64;

  for (int qc = wave; qc < nchunk; qc += 4) {
    const u16* qp = qsel + qbase + (size_t)(qc * 16 + lr) * NC + lg * 8;
    bf16x8 qf0 = *(const bf16x8*)(qp);
    bf16x8 qf1 = *(const bf16x8*)(qp + 32);

    f32x4 s[6];
    #pragma unroll
    for (int mt = 0; mt < 6; ++mt) s[mt] = (f32x4){0.f,0.f,0.f,0.f};
    #pragma unroll
    for (int mt = 0; mt < 6; ++mt) {
      if (mt < mtmax) {
        const u16* kp = ksel + qbase + (size_t)(mt * 16 + lr) * NC + lg * 8;
        bf16x8 kf0 = *(const bf16x8*)(kp);
        bf16x8 kf1 = *(const bf16x8*)(kp + 32);
        f32x4 a = (f32x4){0.f,0.f,0.f,0.f};
        a = __builtin_amdgcn_mfma_f32_16x16x32_bf16(kf0, qf0, a, 0, 0, 0);
        a = __builtin_amdgcn_mfma_f32_16x16x32_bf16(kf1, qf1, a, 0, 0, 0);
        s[mt] = a;
      }
    }

    float mx = -3e38f;
    #pragma unroll
    for (int mt = 0; mt < 6; ++mt)
      #pragma unroll
      for (int jj = 0; jj < 4; ++jj) {
        int mm = mt*16 + 4*lg + jj;
        float val = (mm < cntb) ? s[mt][jj] * 0.125f : -1e30f;
        s[mt][jj] = val;
        mx = fmaxf(mx, val);
      }
    mx = fmaxf(mx, __shfl_xor(mx, 16));
    mx = fmaxf(mx, __shfl_xor(mx, 32));
    float sum = 0.f;
    #pragma unroll
    for (int mt = 0; mt < 6; ++mt)
      #pragma unroll
      for (int jj = 0; jj < 4; ++jj) {
        float pv = __expf(s[mt][jj] - mx);
        s[mt][jj] = pv;
        sum += pv;
      }
    sum += __shfl_xor(sum, 16);
    sum += __shfl_xor(sum, 32);
    float inv = 1.0f / sum;

    uint32_t u[6][2];
    #pragma unroll
    for (int mt = 0; mt < 6; ++mt) {
      u[mt][0] = ((uint32_t)f2bf(s[mt][1]*inv) << 16) | f2bf(s[mt][0]*inv);
      u[mt][1] = ((uint32_t)f2bf(s[mt][3]*inv) << 16) | f2bf(s[mt][2]*inv);
    }

    f32x4 oacc[4];
    #pragma unroll
    for (int dt = 0; dt < 4; ++dt) oacc[dt] = (f32x4){0.f,0.f,0.f,0.f};
    #pragma unroll
    for (int mc = 0; mc < 3; ++mc) {
      if (mc < mcmax) {
        uint32_t a0 = (uint32_t)__builtin_amdgcn_ds_bpermute(idx0, (int)u[2*mc][0]);
        uint32_t b0 = (uint32_t)__builtin_amdgcn_ds_bpermute(idx0, (int)u[2*mc+1][0]);
        uint32_t a1 = (uint32_t)__builtin_amdgcn_ds_bpermute(idx0, (int)u[2*mc][1]);
        uint32_t b1 = (uint32_t)__builtin_amdgcn_ds_bpermute(idx0, (int)u[2*mc+1][1]);
        uint32_t a2 = (uint32_t)__builtin_amdgcn_ds_bpermute(idx1, (int)u[2*mc][0]);
        uint32_t b2 = (uint32_t)__builtin_amdgcn_ds_bpermute(idx1, (int)u[2*mc+1][0]);
        uint32_t a3 = (uint32_t)__builtin_amdgcn_ds_bpermute(idx1, (int)u[2*mc][1]);
        uint32_t b3 = (uint32_t)__builtin_amdgcn_ds_bpermute(idx1, (int)u[2*mc+1][1]);
        bool hi = (lg >= 2);
        union { uint32_t w[4]; bf16x8 v; } pu;
        pu.w[0] = hi ? b0 : a0;
        pu.w[1] = hi ? b1 : a1;
        pu.w[2] = hi ? b2 : a2;
        pu.w[3] = hi ? b3 : a3;
        bf16x8 pa = pu.v;
        #pragma unroll
        for (int dt = 0; dt < 4; ++dt) {
          bf16x8 vf = *(const bf16x8*)(&Vt[dt*16 + lr][mc*32 + lg*8]);
          oacc[dt] = __builtin_amdgcn_mfma_f32_16x16x32_bf16(pa, vf, oacc[dt], 0, 0, 0);
        }
      }
    }

    #pragma unroll
    for (int r = 0; r < 4; ++r) {
      int nloc = qc*16 + 4*lg + r;
      if (nloc < cntb) {
        u16* op = zsel + qbase + (size_t)nloc * NC + lr;
        #pragma unroll
        for (int dt = 0; dt < 4; ++dt)
          op[dt*16] = f2bf(oacc[dt][r]);
      }
    }
  }
}

// ===================== K4: dense fused GEMM (594) | proj-global (288) =======
#define DBLK 594   // 99 m-tiles x 6 n-tiles, XCD-chunked (q=74, r=2)
#define PJBLK (MSELT*6)  // 288
__global__ __launch_bounds__(256) void k4_out(const u16* __restrict__ xb,
    const u16* __restrict__ wvpb, const u16* __restrict__ zsel,
    const u16* __restrict__ wpb, const float* __restrict__ ts,
    const float* __restrict__ bp, float* __restrict__ out,
    const int* __restrict__ boff, const int* __restrict__ gidx) {
  alignas(16) __shared__ u16 SA[3][128][32];
  alignas(16) __shared__ u16 SB[3][128][32];
  int bid = blockIdx.x;
  if (bid < DBLK) {
    int xcd = bid & 7, loc = bid >> 3;
    int wgid = (xcd < 2 ? xcd * 75 : 150 + (xcd - 2) * 74) + loc;
    gemm128c<0, 1>(xb, wvpb, nullptr, out, bp, ts, nullptr,
                   (wgid / 6) * 128, (wgid % 6) * 128, NM, SA, SB);
  } else {
    int pid = bid - DBLK;
    int mt = pid / 6, y = pid % 6;
    int total = boff[NB];
    int m0 = mt * 128;
    if (m0 >= total) return;
    gemm128c<0, 2>(zsel, wpb, nullptr, out, bp, nullptr,
                   gidx, m0, y * 128, total, SA, SB);
  }
}

// ---------------------------------------------------------------------------
extern "C" void kernel_launch(void* const* d_in, const int* in_sizes, int n_in,
                              void* d_out, int out_size, void* d_ws, size_t ws_size,
                              hipStream_t stream) {
  const float* x  = (const float*)d_in[0];
  const float* g1 = (const float*)d_in[1];
  const float* g2 = (const float*)d_in[2];
  const float* Wq = (const float*)d_in[3];
  const float* Wk = (const float*)d_in[4];
  const float* Wv = (const float*)d_in[5];
  const float* Wp = (const float*)d_in[6];
  const float* bp = (const float*)d_in[7];
  const float* Wm = (const float*)d_in[8];
  const float* bm = (const float*)d_in[9];
  float* out = (float*)d_out;

  const size_t act_sz = ASZ * 2;
  const size_t w_sz   = WSZ * 2;
  const size_t sel_sz = SELSZ2 * 2;
  size_t need = act_sz + 4*sel_sz + 6*w_sz + (size_t)NM*4
              + (size_t)(NB+1)*4 + (size_t)NB*4 + (size_t)SELR*4 + 256;
  if (ws_size < need) return;

  char* p = (char*)d_ws;
  u16* xb   = (u16*)p; p += act_sz;
  u16* qsel = (u16*)p; p += sel_sz;    // qsel,ksel,vsel consecutive (z*SELSZ2)
  u16* ksel = (u16*)p; p += sel_sz;
  u16* vsel = (u16*)p; p += sel_sz;
  u16* zsel = (u16*)p; p += sel_sz;
  u16* wqb  = (u16*)p; p += w_sz;      // wqb,wkb,wvb consecutive (z*WSZ)
  u16* wkb  = (u16*)p; p += w_sz;
  u16* wvb  = (u16*)p; p += w_sz;
  u16* wpb  = (u16*)p; p += w_sz;
  u16* wvtb = (u16*)p; p += w_sz;      // Wv^T bf16
  u16* wvpb = (u16*)p; p += w_sz;      // Wvp = Wp @ Wv
  float* ts = (float*)p; p += (size_t)NM*4;
  int* cnt  = (int*)p;  p += (size_t)NB*4;
  int* boff = (int*)p;  p += (size_t)(NB+1)*4;
  int* gidx = (int*)p;
  (void)wkb; (void)wvb;

  // K1: fused gate+cvt-x | cvt weights | trans Wv
  k1_prep<<<dim3(GATEB + 4*WBLK + TRBLK), 256, 0, stream>>>(
      x, g1, g2, Wm, bm, Wq, Wk, Wv, Wp,
      xb, wqb, wkb, wvb, wpb, wvtb, ts);

  // CK: parallel global compaction (single 1024-thread block)
  ck_compact<<<dim3(1), 1024, 0, stream>>>(ts, cnt, boff, gidx);

  // K2: gemm_sel-global Q/K/V | Wvp GEMM (counted-vmcnt bodies)
  k2_wvp_qkv<<<dim3(MSELT*18 + 36), 256, 0, stream>>>(
      xb, wqb, wpb, wvtb, wvpb, qsel, boff, gidx);

  // K3: sparse attention -> compact zsel
  attn_sel<<<dim3(NB*NH), 256, 0, stream>>>(qsel, ksel, vsel, zsel, cnt, boff);

  // K4: dense fused out (unselected) | proj-global scatter (selected)
  k4_out<<<dim3(DBLK + PJBLK), 256, 0, stream>>>(
      xb, wvpb, zsel, wpb, ts, bp, out, boff, gidx);
}